// Round 4
// baseline (3736.167 us; speedup 1.0000x reference)
//
#include <hip/hip_runtime.h>
#include <cstdint>

#define NN 300000
#define NE 600000
#define HD 128
#define NL 5
#define NG 8192
#define AVOC 128
#define BVOC 8
#define NAF 9
#define NBF 3
#define BN_EPS 1e-5f

#define SCAN_B 2048
#define SCAN_NB ((NN + SCAN_B - 1) / SCAN_B)   // 147

#define GEMM_NBLK 1875
#define GEMM_TILES 5            // 1875 * 5 * 32 == 300000 exactly

typedef unsigned short u16;
typedef unsigned int u32;
typedef __attribute__((ext_vector_type(4))) short v4s;
typedef __attribute__((ext_vector_type(8))) short v8s;
typedef __attribute__((ext_vector_type(16))) float v16f;

static __device__ __forceinline__ void atomAddF(float* p, float v) { unsafeAtomicAdd(p, v); }

static __device__ __forceinline__ float bf2f(u16 v) {
  union { u32 u; float f; } c; c.u = ((u32)v) << 16; return c.f;
}
static __device__ __forceinline__ u16 f2bf(float f) {
  union { float f; u32 u; } c; c.f = f;
  u32 u = c.u;
  return (u16)((u + 0x7FFFu + ((u >> 16) & 1u)) >> 16);  // RNE
}
static __device__ __forceinline__ void unp8(uint4 p, float* v) {
  v[0] = bf2f((u16)(p.x & 0xffff)); v[1] = bf2f((u16)(p.x >> 16));
  v[2] = bf2f((u16)(p.y & 0xffff)); v[3] = bf2f((u16)(p.y >> 16));
  v[4] = bf2f((u16)(p.z & 0xffff)); v[5] = bf2f((u16)(p.z >> 16));
  v[6] = bf2f((u16)(p.w & 0xffff)); v[7] = bf2f((u16)(p.w >> 16));
}
static __device__ __forceinline__ uint4 pk8(const float* v) {
  uint4 p;
  p.x = ((u32)f2bf(v[1]) << 16) | f2bf(v[0]);
  p.y = ((u32)f2bf(v[3]) << 16) | f2bf(v[2]);
  p.z = ((u32)f2bf(v[5]) << 16) | f2bf(v[4]);
  p.w = ((u32)f2bf(v[7]) << 16) | f2bf(v[6]);
  return p;
}
static __device__ __forceinline__ uint4 pku(const u16* v) {
  uint4 p;
  p.x = ((u32)v[1] << 16) | v[0]; p.y = ((u32)v[3] << 16) | v[2];
  p.z = ((u32)v[5] << 16) | v[4]; p.w = ((u32)v[7] << 16) | v[6];
  return p;
}
static __device__ __forceinline__ v8s lds8(const u16* p) {
  v4s a = *(const v4s*)p;
  v4s b = *(const v4s*)(p + 4);
  v8s r;
  r[0] = a[0]; r[1] = a[1]; r[2] = a[2]; r[3] = a[3];
  r[4] = b[0]; r[5] = b[1]; r[6] = b[2]; r[7] = b[3];
  return r;
}

// ================= CSR construction =================
__global__ __launch_bounds__(256) void count_k(const int* __restrict__ ei,
    int* __restrict__ cnt_row, int* __restrict__ cnt_col) {
  int e = blockIdx.x * 256 + threadIdx.x;
  if (e >= NE) return;
  atomicAdd(&cnt_row[ei[e]], 1);
  atomicAdd(&cnt_col[ei[NE + e]], 1);
}

__global__ __launch_bounds__(256) void scan_block_k(int* __restrict__ P, int* __restrict__ bsum) {
  __shared__ int s[256];
  int b = blockIdx.x, t = threadIdx.x;
  int base = b * SCAN_B + t * 8;
  int v[8]; int ts = 0;
#pragma unroll
  for (int j = 0; j < 8; j++) { v[j] = (base + j < NN) ? P[base + j] : 0; ts += v[j]; }
  s[t] = ts;
  __syncthreads();
  for (int off = 1; off < 256; off <<= 1) {
    int tmp = 0;
    if (t >= off) tmp = s[t - off];
    __syncthreads();
    if (t >= off) s[t] += tmp;
    __syncthreads();
  }
  if (t == 255) bsum[b] = s[255];
  int run = (t == 0) ? 0 : s[t - 1];
#pragma unroll
  for (int j = 0; j < 8; j++) {
    if (base + j < NN) P[base + j] = run;
    run += v[j];
  }
}

__global__ __launch_bounds__(256) void scan_tops_k(int* __restrict__ bsum, int* __restrict__ totOut) {
  __shared__ int s[256];
  int t = threadIdx.x;
  s[t] = (t < SCAN_NB) ? bsum[t] : 0;
  __syncthreads();
  for (int off = 1; off < 256; off <<= 1) {
    int tmp = 0;
    if (t >= off) tmp = s[t - off];
    __syncthreads();
    if (t >= off) s[t] += tmp;
    __syncthreads();
  }
  if (t < SCAN_NB) bsum[t] = (t == 0) ? 0 : s[t - 1];
  if (t == 255) *totOut = s[255];
}

__global__ __launch_bounds__(256) void scan_add_k(int* __restrict__ P, const int* __restrict__ bsum) {
  int b = blockIdx.x, t = threadIdx.x;
  int off = bsum[b];
  int base = b * SCAN_B + t * 8;
#pragma unroll
  for (int j = 0; j < 8; j++)
    if (base + j < NN) P[base + j] += off;
}

__global__ __launch_bounds__(256) void fill_k(const int* __restrict__ ei,
    const int* __restrict__ ptr_row, const int* __restrict__ ptr_col,
    int* __restrict__ fillr, int* __restrict__ fillc,
    int* __restrict__ adj_row, int* __restrict__ adj_col) {
  int e = blockIdx.x * 256 + threadIdx.x;
  if (e >= NE) return;
  int r = ei[e], c = ei[NE + e];
  int p1 = atomicAdd(&fillr[r], 1);
  adj_row[ptr_row[r] + p1] = e;
  int p2 = atomicAdd(&fillc[c], 1);
  adj_col[ptr_col[c] + p2] = r;
}

__global__ __launch_bounds__(256) void inv_k(const int* __restrict__ ptr_row, float* __restrict__ inv) {
  int n = blockIdx.x * 256 + threadIdx.x;
  if (n < NN) inv[n] = 1.0f / ((float)(ptr_row[n + 1] - ptr_row[n]) + 1.0f);
}

__global__ __launch_bounds__(256) void gp_k(const int* __restrict__ batch, int* __restrict__ gp) {
  int g = blockIdx.x * 256 + threadIdx.x;
  if (g > NG) return;
  int lo = 0, hi = NN;
  while (lo < hi) { int mid = (lo + hi) >> 1; if (batch[mid] < g) lo = mid + 1; else hi = mid; }
  gp[g] = lo;
}

// ================= weight prep: split + transpose =================
// wt layout per (layer,gemm): [hi: n*128+k][lo: n*128+k], 32768 u16 each chunk.
__global__ __launch_bounds__(256) void wprep_k(const float* __restrict__ w1,
    const float* __restrict__ w2, u16* __restrict__ wt) {
  int gid = blockIdx.x * 256 + threadIdx.x;
  if (gid >= NL * 2 * 16384) return;
  int lg = gid >> 14;
  int idx = gid & 16383;
  int l = lg >> 1, g = lg & 1;
  int n = idx >> 7, k = idx & 127;
  const float* W = (g ? w2 : w1) + (size_t)l * 16384;
  float x = W[k * 128 + n];
  u16 hi = f2bf(x);
  u16 lo = f2bf(x - bf2f(hi));
  u16* base = wt + (size_t)lg * 32768;
  base[idx] = hi;
  base[16384 + idx] = lo;
}

// ================= model kernels =================
__global__ __launch_bounds__(256) void atom_encoder_k(const int* __restrict__ x,
    const float* __restrict__ emb, u16* __restrict__ A) {
  int gid = blockIdx.x * 256 + threadIdx.x;
  if (gid >= NN * 16) return;
  int n = gid >> 4, c8 = gid & 15;
  float acc[8] = {0.f, 0.f, 0.f, 0.f, 0.f, 0.f, 0.f, 0.f};
#pragma unroll
  for (int f = 0; f < NAF; f++) {
    int v = x[n * NAF + f];
    const float* e = emb + ((size_t)(f * AVOC + v)) * HD + c8 * 8;
    float4 e0 = *(const float4*)e;
    float4 e1 = *(const float4*)(e + 4);
    acc[0] += e0.x; acc[1] += e0.y; acc[2] += e0.z; acc[3] += e0.w;
    acc[4] += e1.x; acc[5] += e1.y; acc[6] += e1.z; acc[7] += e1.w;
  }
  *(uint4*)(A + (size_t)n * HD + c8 * 8) = pk8(acc);
}

// per-node: h_in = h + inv * sum_{in-edges(row)} bond_emb(edge) ; A <- bf16(h_in)
__global__ __launch_bounds__(256) void bond_hin_k(const int* __restrict__ ea,
    const float* __restrict__ be, const int* __restrict__ ptr_row,
    const int* __restrict__ adj_row, const float* __restrict__ inv,
    u16* __restrict__ A) {
  int t = threadIdx.x;
  int n = blockIdx.x * 16 + (t >> 4);
  int c8 = t & 15;
  if (n >= NN) return;
  int beg = ptr_row[n], end = ptr_row[n + 1];
  float acc[8] = {0.f, 0.f, 0.f, 0.f, 0.f, 0.f, 0.f, 0.f};
  for (int i = beg; i < end; i++) {
    int e = adj_row[i];
    int a0 = ea[e * 3 + 0], a1 = ea[e * 3 + 1], a2 = ea[e * 3 + 2];
    const float* p0 = be + (size_t)a0 * HD + c8 * 8;
    const float* p1 = be + (size_t)(BVOC + a1) * HD + c8 * 8;
    const float* p2 = be + (size_t)(2 * BVOC + a2) * HD + c8 * 8;
    float4 x0 = *(const float4*)p0, x1 = *(const float4*)(p0 + 4);
    float4 y0 = *(const float4*)p1, y1 = *(const float4*)(p1 + 4);
    float4 z0 = *(const float4*)p2, z1 = *(const float4*)(p2 + 4);
    acc[0] += x0.x + y0.x + z0.x; acc[1] += x0.y + y0.y + z0.y;
    acc[2] += x0.z + y0.z + z0.z; acc[3] += x0.w + y0.w + z0.w;
    acc[4] += x1.x + y1.x + z1.x; acc[5] += x1.y + y1.y + z1.y;
    acc[6] += x1.z + y1.z + z1.z; acc[7] += x1.w + y1.w + z1.w;
  }
  float iv = inv[n];
  uint4 pa = *(const uint4*)(A + (size_t)n * HD + c8 * 8);
  float h[8]; unp8(pa, h);
#pragma unroll
  for (int j = 0; j < 8; j++) h[j] = fmaf(acc[j], iv, h[j]);
  *(uint4*)(A + (size_t)n * HD + c8 * 8) = pk8(h);
}

// per-node: z = (1+eps)*h_in[n] + sum h_in[src]  -> split bf16 (Zhi, Zlo)
__global__ __launch_bounds__(256) void aggr_z_k(const int* __restrict__ ptr_col,
    const int* __restrict__ adj_col, const u16* __restrict__ A,
    u16* __restrict__ Zhi, u16* __restrict__ Zlo,
    const float* __restrict__ eps, int l) {
  int t = threadIdx.x;
  int n = blockIdx.x * 16 + (t >> 4);
  int c8 = t & 15;
  if (n >= NN) return;
  float s = 1.0f + eps[l];
  uint4 pa = *(const uint4*)(A + (size_t)n * HD + c8 * 8);
  float z[8]; unp8(pa, z);
#pragma unroll
  for (int j = 0; j < 8; j++) z[j] *= s;
  int beg = ptr_col[n], end = ptr_col[n + 1];
  for (int i = beg; i < end; i++) {
    int src = adj_col[i];
    uint4 ps = *(const uint4*)(A + (size_t)src * HD + c8 * 8);
    float v[8]; unp8(ps, v);
#pragma unroll
    for (int j = 0; j < 8; j++) z[j] += v[j];
  }
  u16 hh[8], ll[8];
#pragma unroll
  for (int j = 0; j < 8; j++) {
    hh[j] = f2bf(z[j]);
    ll[j] = f2bf(z[j] - bf2f(hh[j]));
  }
  *(uint4*)(Zhi + (size_t)n * HD + c8 * 8) = pku(hh);
  *(uint4*)(Zlo + (size_t)n * HD + c8 * 8) = pku(ll);
}

// ============ MFMA GEMM: C = f(A) @ W + bias, split-bf16 fp32-accurate ============
// FUSE: A is single bf16 plane; apply relu(x*sc+sh) in staging and split hi/lo.
// !FUSE: A provided as split planes (Ahi, Alo).
// Output: Chi bf16 (always); if SPLIT_OUT also Clo (residual) -> fp32-equivalent C.
// Per-channel sum/sumsq of fp32 C accumulated into stats[0:128)/[128:256).
template<bool FUSE, bool SPLIT_OUT>
__global__ __launch_bounds__(256) void mgemm_k(
    const u16* __restrict__ Ahi, const u16* __restrict__ Alo,
    const u16* __restrict__ wt, const float* __restrict__ bias,
    u16* __restrict__ Chi, u16* __restrict__ Clo,
    float* __restrict__ stats, const float* __restrict__ ss) {
  __shared__ u16 sHi[32 * 132];     // row stride 132 -> conflict-free b64 frag reads
  __shared__ u16 sLo[32 * 132];
  const int tid = threadIdx.x;
  const int lane = tid & 63;
  const int wave = tid >> 6;
  const int m = lane & 31;
  const int quad = lane >> 5;
  const int col = wave * 32 + m;    // 4 waves cover N=128

  // B-fragments in registers, reused across all m-tiles.
  // B[k=(quad)*8+j][n=col] == Wt[col][k] (wt is transposed: n-major)
  v8s bhi[8], blo[8];
#pragma unroll
  for (int s = 0; s < 8; s++) {
    int off = col * 128 + s * 16 + quad * 8;
    bhi[s] = *(const v8s*)(wt + off);
    blo[s] = *(const v8s*)(wt + 16384 + off);
  }
  const float bias_c = bias[col];
  float csum = 0.f, csq = 0.f;

  const int r = tid >> 3;           // staging: 32 rows x 8 slots of 16 bf16
  const int k0 = (tid & 7) * 16;

  for (int it = 0; it < GEMM_TILES; it++) {
    const int mbase = (blockIdx.x + it * GEMM_NBLK) * 32;
    __syncthreads();
    {
      const size_t gbase = (size_t)(mbase + r) * HD + k0;
      u16* dh = sHi + r * 132 + k0;
      u16* dl = sLo + r * 132 + k0;
      if constexpr (FUSE) {
        uint4 p0 = *(const uint4*)(Ahi + gbase);
        uint4 p1 = *(const uint4*)(Ahi + gbase + 8);
        float v[16];
        unp8(p0, v); unp8(p1, v + 8);
#pragma unroll
        for (int jj = 0; jj < 4; jj++) {
          v4s th, tl;
#pragma unroll
          for (int q2 = 0; q2 < 4; q2++) {
            int j = jj * 4 + q2;
            float xx = fmaxf(fmaf(v[j], ss[k0 + j], ss[128 + k0 + j]), 0.f);
            u16 hv = f2bf(xx);
            th[q2] = (short)hv;
            tl[q2] = (short)f2bf(xx - bf2f(hv));
          }
          *(v4s*)(dh + jj * 4) = th;
          *(v4s*)(dl + jj * 4) = tl;
        }
      } else {
        union { uint4 q; v4s h[2]; } u;
        u.q = *(const uint4*)(Ahi + gbase);     *(v4s*)(dh) = u.h[0];      *(v4s*)(dh + 4) = u.h[1];
        u.q = *(const uint4*)(Ahi + gbase + 8); *(v4s*)(dh + 8) = u.h[0];  *(v4s*)(dh + 12) = u.h[1];
        u.q = *(const uint4*)(Alo + gbase);     *(v4s*)(dl) = u.h[0];      *(v4s*)(dl + 4) = u.h[1];
        u.q = *(const uint4*)(Alo + gbase + 8); *(v4s*)(dl + 8) = u.h[0];  *(v4s*)(dl + 12) = u.h[1];
      }
    }
    __syncthreads();

    v16f acc;
#pragma unroll
    for (int i = 0; i < 16; i++) acc[i] = 0.f;
#pragma unroll
    for (int s = 0; s < 8; s++) {
      // A[m][k=quad*8+j] from LDS
      const u16* pa = sHi + m * 132 + s * 16 + quad * 8;
      const u16* pl = sLo + m * 132 + s * 16 + quad * 8;
      v8s ah = lds8(pa);
      v8s al = lds8(pl);
      acc = __builtin_amdgcn_mfma_f32_32x32x16_bf16(ah, bhi[s], acc, 0, 0, 0);
      acc = __builtin_amdgcn_mfma_f32_32x32x16_bf16(ah, blo[s], acc, 0, 0, 0);
      acc = __builtin_amdgcn_mfma_f32_32x32x16_bf16(al, bhi[s], acc, 0, 0, 0);
    }
    // C/D layout (verified m74/m101): col = lane&31, row = (reg&3)+8*(reg>>2)+4*quad
#pragma unroll
    for (int rr = 0; rr < 16; rr++) {
      int row = (rr & 3) + 8 * (rr >> 2) + 4 * quad;
      size_t g = (size_t)(mbase + row) * HD + col;
      float o = acc[rr] + bias_c;
      csum += o; csq += o * o;
      u16 hv = f2bf(o);
      Chi[g] = hv;
      if constexpr (SPLIT_OUT) Clo[g] = f2bf(o - bf2f(hv));
    }
  }
  atomAddF(&stats[col], csum);
  atomAddF(&stats[HD + col], csq);
}

__global__ __launch_bounds__(128) void scale_shift_k(float* __restrict__ stats,
    const float* __restrict__ g, const float* __restrict__ b) {
  int c = threadIdx.x;
  float mean = stats[c] * (1.0f / NN);
  float var = stats[HD + c] * (1.0f / NN) - mean * mean;
  float sc = g[c] * rsqrtf(var + BN_EPS);
  stats[256 + c] = sc;
  stats[384 + c] = fmaf(-mean, sc, b[c]);
}

// BN apply on split (Zhi+Zlo) -> A (bf16) (+relu)
__global__ __launch_bounds__(256) void bn_apply_k(const u16* __restrict__ Zhi,
    const u16* __restrict__ Zlo, u16* __restrict__ A,
    const float* __restrict__ ss, int relu) {
  int gid = blockIdx.x * 256 + threadIdx.x;
  if (gid >= NN * 16) return;
  int n = gid >> 4, c8 = gid & 15;
  uint4 ph = *(const uint4*)(Zhi + (size_t)n * HD + c8 * 8);
  uint4 pl = *(const uint4*)(Zlo + (size_t)n * HD + c8 * 8);
  float vh[8], vl[8];
  unp8(ph, vh); unp8(pl, vl);
  float v[8];
#pragma unroll
  for (int j = 0; j < 8; j++) {
    v[j] = fmaf(vh[j] + vl[j], ss[c8 * 8 + j], ss[128 + c8 * 8 + j]);
    if (relu) v[j] = fmaxf(v[j], 0.f);
  }
  *(uint4*)(A + (size_t)n * HD + c8 * 8) = pk8(v);
}

// fused global_add_pool + 2-layer MLP head; one block per graph
__global__ __launch_bounds__(128) void pool_final_k(const u16* __restrict__ A,
    const int* __restrict__ gp, const float* __restrict__ cw1,
    const float* __restrict__ cb1, const float* __restrict__ cw2,
    const float* __restrict__ cb2, float* __restrict__ out) {
  __shared__ float sp[128];
  __shared__ float sh[128];
  int g = blockIdx.x, t = threadIdx.x;
  int beg = gp[g], end = gp[g + 1];
  float acc = 0.f;
  for (int n = beg; n < end; n++) acc += bf2f(A[(size_t)n * HD + t]);
  sp[t] = acc;
  __syncthreads();
  float h1 = cb1[t];
#pragma unroll
  for (int k = 0; k < HD; k++) h1 = fmaf(sp[k], cw1[k * HD + t], h1);
  h1 = fmaxf(h1, 0.f);
  sh[t] = h1 * cw2[t];
  __syncthreads();
  for (int s = 64; s >= 1; s >>= 1) {
    if (t < s) sh[t] += sh[t + s];
    __syncthreads();
  }
  if (t == 0) out[g] = sh[0] + cb2[0];
}

extern "C" void kernel_launch(void* const* d_in, const int* in_sizes, int n_in,
                              void* d_out, int out_size, void* d_ws, size_t ws_size,
                              hipStream_t stream) {
  const int*   x        = (const int*)d_in[0];
  const int*   ei       = (const int*)d_in[1];
  const int*   ea       = (const int*)d_in[2];
  const int*   batch    = (const int*)d_in[3];
  const float* atom_emb = (const float*)d_in[4];
  const float* bond_emb = (const float*)d_in[5];
  const float* eps      = (const float*)d_in[6];
  const float* w1       = (const float*)d_in[7];
  const float* b1       = (const float*)d_in[8];
  const float* bn1_g    = (const float*)d_in[9];
  const float* bn1_b    = (const float*)d_in[10];
  const float* w2       = (const float*)d_in[11];
  const float* b2       = (const float*)d_in[12];
  const float* bn_g     = (const float*)d_in[13];
  const float* bn_b     = (const float*)d_in[14];
  const float* cw1      = (const float*)d_in[15];
  const float* cb1      = (const float*)d_in[16];
  const float* cw2      = (const float*)d_in[17];
  const float* cb2      = (const float*)d_in[18];
  float* out = (float*)d_out;

  const size_t NH = (size_t)NN * HD;
  float* ws = (float*)d_ws;
  float* stats   = ws;                               // 5*1024 floats
  u16*   wt      = (u16*)(stats + 5 * 1024);         // 10*32768 u16 = 655360 B
  int*   ptr_row = (int*)(wt + 10 * 32768);          // NN+1
  int*   ptr_col = ptr_row + (NN + 1);               // NN+1
  int*   adj_row = ptr_col + (NN + 1);               // NE
  int*   adj_col = adj_row + NE;                     // NE
  int*   gp      = adj_col + NE;                     // NG+1
  float* inv     = (float*)(gp + (NG + 1));          // NN
  size_t off = (size_t)(inv - ws) + NN;
  off = (off + 3) & ~(size_t)3;                      // 16B align
  u16* A   = (u16*)(ws + off);                       // NH bf16
  u16* Zhi = A + NH;                                 // NH bf16
  u16* Zlo = Zhi + NH;                               // NH bf16
  // setup-only temps aliased into Zhi (first written by aggr_z, after fill_k)
  int* fillr = (int*)Zhi;
  int* fillc = fillr + NN;
  int* bsums = fillc + NN;

  const int nb_n16 = (int)(((size_t)NN * 16 + 255) / 256);  // 18750
  const int nb_node = (NN + 15) / 16;                        // 18750
  const int nb_e  = (NE + 255) / 256;                        // 2344

  // ---- setup ----
  hipMemsetAsync(stats, 0, 5 * 1024 * sizeof(float), stream);
  hipMemsetAsync(ptr_row, 0, 2 * (NN + 1) * sizeof(int), stream);
  hipMemsetAsync(fillr, 0, 2 * NN * sizeof(int), stream);

  wprep_k<<<(NL * 2 * 16384 + 255) / 256, 256, 0, stream>>>(w1, w2, wt);
  count_k<<<nb_e, 256, 0, stream>>>(ei, ptr_row, ptr_col);
  scan_block_k<<<SCAN_NB, 256, 0, stream>>>(ptr_row, bsums);
  scan_tops_k<<<1, 256, 0, stream>>>(bsums, &ptr_row[NN]);
  scan_add_k<<<SCAN_NB, 256, 0, stream>>>(ptr_row, bsums);
  scan_block_k<<<SCAN_NB, 256, 0, stream>>>(ptr_col, bsums);
  scan_tops_k<<<1, 256, 0, stream>>>(bsums, &ptr_col[NN]);
  scan_add_k<<<SCAN_NB, 256, 0, stream>>>(ptr_col, bsums);
  inv_k<<<(NN + 255) / 256, 256, 0, stream>>>(ptr_row, inv);
  fill_k<<<nb_e, 256, 0, stream>>>(ei, ptr_row, ptr_col, fillr, fillc, adj_row, adj_col);
  atom_encoder_k<<<nb_n16, 256, 0, stream>>>(x, atom_emb, A);
  gp_k<<<(NG + 1 + 255) / 256, 256, 0, stream>>>(batch, gp);

  // ---- layers ----
  for (int l = 0; l < NL; l++) {
    const float* be = bond_emb + (size_t)l * NBF * BVOC * HD;
    float* st = stats + (size_t)l * 1024;
    bond_hin_k<<<nb_node, 256, 0, stream>>>(ea, be, ptr_row, adj_row, inv, A);
    aggr_z_k<<<nb_node, 256, 0, stream>>>(ptr_col, adj_col, A, Zhi, Zlo, eps, l);
    // GEMM1: z @ w1 + b1 -> A (bf16), stats[0:256)
    mgemm_k<false, false><<<GEMM_NBLK, 256, 0, stream>>>(
        Zhi, Zlo, wt + (size_t)(l * 2 + 0) * 32768, b1 + (size_t)l * HD,
        A, nullptr, st, nullptr);
    scale_shift_k<<<1, 128, 0, stream>>>(st, bn1_g + (size_t)l * HD, bn1_b + (size_t)l * HD);
    // GEMM2: relu(bn1(A)) @ w2 + b2 -> (Zhi, Zlo) split, stats[512:768)
    mgemm_k<true, true><<<GEMM_NBLK, 256, 0, stream>>>(
        A, nullptr, wt + (size_t)(l * 2 + 1) * 32768, b2 + (size_t)l * HD,
        Zhi, Zlo, st + 512, st + 256);
    scale_shift_k<<<1, 128, 0, stream>>>(st + 512, bn_g + (size_t)l * HD, bn_b + (size_t)l * HD);
    // A <- bn(Zhi+Zlo) (+relu except last)
    bn_apply_k<<<nb_n16, 256, 0, stream>>>(Zhi, Zlo, A, st + 768, (l < NL - 1) ? 1 : 0);
  }

  // ---- pooled head ----
  pool_final_k<<<NG, 128, 0, stream>>>(A, gp, cw1, cb1, cw2, cb2, out);
}